// Round 3
// baseline (306.063 us; speedup 1.0000x reference)
//
#include <hip/hip_runtime.h>
#include <math.h>

// Problem constants
#define B_  4
#define L_  8192
#define D_  512

// MFMA GEMM tiling
#define BM   128
#define NCT  4                 // col tiles of 128
#define NRT  (L_ / BM)         // 64
#define NSTEP 16               // K = 512 / 32

// Scan chunking
#define CHUNK 64
#define NCHUNK (L_ / CHUNK)    // 128

#define MAXFIX 16380
#define FIX_TAU 1.5e-3f
#define FROWS 8

typedef short bf16x8 __attribute__((ext_vector_type(8)));
typedef float f32x4 __attribute__((ext_vector_type(4)));
typedef unsigned short u16;
typedef u16 ushort8 __attribute__((ext_vector_type(8)));
typedef unsigned int u32;

__device__ __forceinline__ u16 f2bf_rne(float f) {
    unsigned u = __float_as_uint(f);
    unsigned r = (u + 0x7FFFu + ((u >> 16) & 1u)) >> 16;
    return (u16)r;
}

__device__ __forceinline__ ushort8 cvt8(float4 a, float4 b) {
    ushort8 r;
    r[0] = f2bf_rne(a.x); r[1] = f2bf_rne(a.y);
    r[2] = f2bf_rne(a.z); r[3] = f2bf_rne(a.w);
    r[4] = f2bf_rne(b.x); r[5] = f2bf_rne(b.y);
    r[6] = f2bf_rne(b.z); r[7] = f2bf_rne(b.w);
    return r;
}

__device__ __forceinline__ ushort8 ldcvt(const float* p) {
    float4 a = *(const float4*)p;
    float4 b = *(const float4*)(p + 4);
    return cvt8(a, b);
}

// ---------------------------------------------------------------------------
// Weight conversion: fp32 -> bf16 (hi only)
// ---------------------------------------------------------------------------
__global__ __launch_bounds__(256) void conv_w(
    const float* __restrict__ wq, const float* __restrict__ wk,
    u16* __restrict__ qh, u16* __restrict__ kh)
{
    int i = blockIdx.x * 256 + threadIdx.x;
    if (i >= D_ * D_) return;
    qh[i] = f2bf_rne(wq[i]);
    kh[i] = f2bf_rne(wk[i]);
}

__global__ void zero_fix(int* c) { if (threadIdx.x == 0 && blockIdx.x == 0) *c = 0; }

// ---------------------------------------------------------------------------
// Shared-A bf16 MFMA kernel.
// Per block: 128 rows x 128 cols of Q = h@Wq^T and K = h@Wk^T.
// Partials per row r (over block's 128 cols):
//   slot0: nq[r] = sum Q[r,c]^2
//   slot1: nk[r] = sum K[r,c]^2      (indexed by K-row; shift applied later)
//   slot2: dot[r] = sum Q[r,c]*K[r+1,c]   (row shift done in registers)
// part layout: [NCT][B][L][3]
// ---------------------------------------------------------------------------
__global__ __launch_bounds__(256, 2) void qk_mfma(
    const float* __restrict__ h,
    const u16* __restrict__ wqh, const u16* __restrict__ wkh,
    float* __restrict__ part)
{
    const int ct = blockIdx.x, rt = blockIdx.y, b = blockIdx.z;
    const int t = threadIdx.x, wid = t >> 6, lane = t & 63;
    const int l15 = lane & 15, l4 = lane >> 4;

    __shared__ __align__(16) u16 ah[144 * 32];   // rows 0..128 data; 129..143 zero
    __shared__ float red[4][BM][3];

    if (t < 240) ((u32*)ah)[2064 + t] = 0;       // zero rows 129..143

    const int r0 = rt * BM;
    const float* hb = h + (size_t)b * L_ * D_;

    // staging: 512 chunks of 8 floats (rows 0..127), +4 chunks for row 128
    const float* sp0 = hb + (size_t)(r0 + (t >> 2)) * D_ + (t & 3) * 8;
    const float* sp1 = hb + (size_t)(r0 + 64 + (t >> 2)) * D_ + (t & 3) * 8;
    int r128 = r0 + BM; if (r128 > L_ - 1) r128 = L_ - 1;
    const float* sp2 = hb + (size_t)r128 * D_ + (t & 3) * 8;   // t<4

    const int colb = ct * 128 + wid * 32;
    const u16* bq0 = wqh + (size_t)(colb + l15) * D_ + l4 * 8;
    const u16* bq1 = bq0 + (size_t)16 * D_;
    const u16* bk0 = wkh + (size_t)(colb + l15) * D_ + l4 * 8;
    const u16* bk1 = bk0 + (size_t)16 * D_;

    f32x4 accq[8][2], acck[8][2], ackl[2];
    const f32x4 zero = {0.f, 0.f, 0.f, 0.f};
#pragma unroll
    for (int rf = 0; rf < 8; ++rf) {
        accq[rf][0] = zero; accq[rf][1] = zero;
        acck[rf][0] = zero; acck[rf][1] = zero;
    }
    ackl[0] = zero; ackl[1] = zero;

    // preload step 0
    ushort8 c0 = ldcvt(sp0);
    ushort8 c1 = ldcvt(sp1);
    ushort8 c2 = {0,0,0,0,0,0,0,0};
    if (t < 4) c2 = ldcvt(sp2);

    for (int s = 0; s < NSTEP; ++s) {
        const int so = s * 32;
        __syncthreads();                      // prior step's LDS reads done
        *(ushort8*)(&ah[t * 8]) = c0;
        *(ushort8*)(&ah[(t + 256) * 8]) = c1;
        if (t < 4) *(ushort8*)(&ah[(512 + t) * 8]) = c2;
        __syncthreads();

        // B fragments for this step (L2-resident weights)
        bf16x8 fbq0 = *(const bf16x8*)(bq0 + so);
        bf16x8 fbq1 = *(const bf16x8*)(bq1 + so);
        bf16x8 fbk0 = *(const bf16x8*)(bk0 + so);
        bf16x8 fbk1 = *(const bf16x8*)(bk1 + so);

        // prefetch next step's A data (latency hides under MFMAs)
        const int sn = (s + 1 < NSTEP) ? (s + 1) * 32 : s * 32;
        c0 = ldcvt(sp0 + sn);
        c1 = ldcvt(sp1 + sn);
        if (t < 4) c2 = ldcvt(sp2 + sn);

#pragma unroll
        for (int rf = 0; rf < 8; ++rf) {
            bf16x8 a = *(const bf16x8*)(&ah[(rf * 16 + l15) * 32 + l4 * 8]);
            accq[rf][0] = __builtin_amdgcn_mfma_f32_16x16x32_bf16(a, fbq0, accq[rf][0], 0, 0, 0);
            accq[rf][1] = __builtin_amdgcn_mfma_f32_16x16x32_bf16(a, fbq1, accq[rf][1], 0, 0, 0);
            acck[rf][0] = __builtin_amdgcn_mfma_f32_16x16x32_bf16(a, fbk0, acck[rf][0], 0, 0, 0);
            acck[rf][1] = __builtin_amdgcn_mfma_f32_16x16x32_bf16(a, fbk1, acck[rf][1], 0, 0, 0);
        }
        bf16x8 al = *(const bf16x8*)(&ah[(128 + l15) * 32 + l4 * 8]);
        ackl[0] = __builtin_amdgcn_mfma_f32_16x16x32_bf16(al, fbk0, ackl[0], 0, 0, 0);
        ackl[1] = __builtin_amdgcn_mfma_f32_16x16x32_bf16(al, fbk1, ackl[1], 0, 0, 0);
    }

    // epilogue: per-row partials. C/D layout: col=lane&15, row=(lane>>4)*4+reg.
#pragma unroll
    for (int rf = 0; rf < 8; ++rf) {
#pragma unroll
        for (int reg = 0; reg < 4; ++reg) {
            float pq = 0.f, pk = 0.f, pd = 0.f;
#pragma unroll
            for (int cf = 0; cf < 2; ++cf) {
                float q  = accq[rf][cf][reg];
                float kv = acck[rf][cf][reg];
                pq += q * q;
                pk += kv * kv;
                float ksh;
                if (reg < 3) {
                    ksh = acck[rf][cf][reg + 1];
                } else {
                    float up = __shfl(acck[rf][cf][0], (lane + 16) & 63);
                    float nx0 = (rf < 7) ? acck[rf + 1][cf][0] : ackl[cf][0];
                    float nx = __shfl(nx0, l15);
                    ksh = (l4 == 3) ? nx : up;
                }
                pd += q * ksh;
            }
#pragma unroll
            for (int off = 1; off < 16; off <<= 1) {
                pq += __shfl_xor(pq, off);
                pk += __shfl_xor(pk, off);
                pd += __shfl_xor(pd, off);
            }
            if (l15 == 0) {
                int row = rf * 16 + l4 * 4 + reg;
                red[wid][row][0] = pq;
                red[wid][row][1] = pk;
                red[wid][row][2] = pd;
            }
        }
    }
    __syncthreads();
    if (t < BM) {
        float pq = red[0][t][0] + red[1][t][0] + red[2][t][0] + red[3][t][0];
        float pk = red[0][t][1] + red[1][t][1] + red[2][t][1] + red[3][t][1];
        float pd = red[0][t][2] + red[1][t][2] + red[2][t][2] + red[3][t][2];
        size_t o = (((size_t)ct * B_ + b) * L_ + (r0 + t)) * 3;
        part[o + 0] = pq; part[o + 1] = pk; part[o + 2] = pd;
    }
}

// ---------------------------------------------------------------------------
// reduce partials -> p (nk read shifted by one row); flag borderline rows
// ---------------------------------------------------------------------------
__global__ __launch_bounds__(256) void cos_reduce(
    const float* __restrict__ part, float* __restrict__ p,
    int* __restrict__ fix_cnt, int* __restrict__ fix_list)
{
    int idx = blockIdx.x * 256 + threadIdx.x;
    if (idx >= B_ * L_) return;
    int b = idx / L_;
    int tp = idx % L_;
    if (tp == 0) { p[idx] = 1.0f; return; }
    int l = tp - 1;
    float nq = 0.f, nk = 0.f, dt = 0.f;
#pragma unroll
    for (int ct = 0; ct < NCT; ++ct) {
        size_t o = (((size_t)ct * B_ + b) * L_ + l) * 3;
        nq += part[o + 0];
        dt += part[o + 2];
        nk += part[o + 4];        // part[...][l+1][1]
    }
    float qn = sqrtf(nq); if (qn < 1e-12f) qn = 1e-12f;
    float kn = sqrtf(nk); if (kn < 1e-12f) kn = 1e-12f;
    float cs = dt / (qn * kn);
    float pr = 0.5f * (1.0f - cs);
    pr = fminf(fmaxf(pr, 0.0f), 1.0f);
    p[idx] = pr;
    if (fabsf(cs) < FIX_TAU) {
        int slot = atomicAdd(fix_cnt, 1);
        if (slot < MAXFIX) fix_list[slot] = idx;
    }
}

// ---------------------------------------------------------------------------
// fp32 fixup of borderline rows, batched FROWS rows per block
// ---------------------------------------------------------------------------
__global__ __launch_bounds__(256) void fixup(
    const float* __restrict__ h, const float* __restrict__ wq,
    const float* __restrict__ wk, const int* __restrict__ fix_cnt,
    const int* __restrict__ fix_list, float* __restrict__ p)
{
    __shared__ float hq[FROWS][D_], hk[FROWS][D_];
    __shared__ float redm[FROWS][3][4];
    const int t = threadIdx.x, wid = t >> 6, lane = t & 63;
    int n = *fix_cnt; if (n > MAXFIX) n = MAXFIX;
    int nb = (n + FROWS - 1) / FROWS;
    for (int bt = blockIdx.x; bt < nb; bt += gridDim.x) {
        int base = bt * FROWS;
        int cnt = n - base; if (cnt > FROWS) cnt = FROWS;
        __syncthreads();
        for (int r = 0; r < cnt; ++r) {
            int idx = fix_list[base + r];
            int bb = idx / L_, tp = idx % L_, l = tp - 1;
            const float* hr = h + ((size_t)bb * L_ + l) * D_;
            for (int i = t; i < D_; i += 256) { hq[r][i] = hr[i]; hk[r][i] = hr[i + D_]; }
        }
        __syncthreads();
        float qv0[FROWS], qv1[FROWS], kv0[FROWS], kv1[FROWS];
#pragma unroll
        for (int r = 0; r < FROWS; ++r) { qv0[r] = qv1[r] = kv0[r] = kv1[r] = 0.f; }
        const float* wqr0 = wq + (size_t)t * D_;
        const float* wqr1 = wq + (size_t)(t + 256) * D_;
        const float* wkr0 = wk + (size_t)t * D_;
        const float* wkr1 = wk + (size_t)(t + 256) * D_;
        for (int k = 0; k < D_; ++k) {
            float w0 = wqr0[k], w1 = wqr1[k], x0 = wkr0[k], x1 = wkr1[k];
#pragma unroll
            for (int r = 0; r < FROWS; ++r) {
                float hqv = hq[r][k], hkv = hk[r][k];
                qv0[r] += hqv * w0; qv1[r] += hqv * w1;
                kv0[r] += hkv * x0; kv1[r] += hkv * x1;
            }
        }
#pragma unroll
        for (int r = 0; r < FROWS; ++r) {
            float pq = qv0[r] * qv0[r] + qv1[r] * qv1[r];
            float pk = kv0[r] * kv0[r] + kv1[r] * kv1[r];
            float pd = qv0[r] * kv0[r] + qv1[r] * kv1[r];
#pragma unroll
            for (int off = 1; off < 64; off <<= 1) {
                pq += __shfl_xor(pq, off);
                pk += __shfl_xor(pk, off);
                pd += __shfl_xor(pd, off);
            }
            if (lane == 0) { redm[r][0][wid] = pq; redm[r][1][wid] = pk; redm[r][2][wid] = pd; }
        }
        __syncthreads();
        if (t < cnt) {
            int r = t;
            float nq = redm[r][0][0] + redm[r][0][1] + redm[r][0][2] + redm[r][0][3];
            float nk = redm[r][1][0] + redm[r][1][1] + redm[r][1][2] + redm[r][1][3];
            float dt = redm[r][2][0] + redm[r][2][1] + redm[r][2][2] + redm[r][2][3];
            float qn = sqrtf(nq); if (qn < 1e-12f) qn = 1e-12f;
            float kn = sqrtf(nk); if (kn < 1e-12f) kn = 1e-12f;
            float cs = dt / (qn * kn);
            float pr = 0.5f * (1.0f - cs);
            pr = fminf(fmaxf(pr, 0.0f), 1.0f);
            p[fix_list[base + r]] = pr;
        }
    }
}

// ---------------------------------------------------------------------------
// EMA scan, float2 per thread, branchless (unconditional loads => pipelined)
// ---------------------------------------------------------------------------
__global__ __launch_bounds__(256) void scan_a(
    const float* __restrict__ h, const float* __restrict__ p,
    float* __restrict__ Bc, float* __restrict__ Ac)
{
    const int t = threadIdx.x;
    const int c = blockIdx.x, b = blockIdx.y;
    const int l0 = c * CHUNK;
    const float* pb = p + (size_t)b * L_ + l0;
    const float2* hb = (const float2*)(h + ((size_t)b * L_ + l0) * D_) + t;

    float2 st = {0.f, 0.f};
    float ap = 1.f;
#pragma unroll 4
    for (int i = 0; i < CHUNK; ++i) {
        float pr = pb[i];
        float2 hv = hb[(size_t)i * 256];
        bool sel = pr > 0.5f;
        float a = sel ? 1.f - pr : 1.f;
        float g = sel ? pr : 0.f;
        st.x = a * st.x + g * hv.x;
        st.y = a * st.y + g * hv.y;
        ap *= a;
    }
    ((float2*)Bc)[((size_t)b * NCHUNK + c) * 256 + t] = st;
    if (t == 0) Ac[b * NCHUNK + c] = ap;
}

__global__ __launch_bounds__(256) void scan_b(
    const float* __restrict__ Ac, const float* __restrict__ Bc,
    const float* __restrict__ det, float* __restrict__ carry)
{
    const int t = threadIdx.x;
    const int b = blockIdx.x;
    float2 st = ((const float2*)det)[(size_t)b * 256 + t];
    for (int c = 0; c < NCHUNK; ++c) {
        ((float2*)carry)[((size_t)b * NCHUNK + c) * 256 + t] = st;
        float a = Ac[b * NCHUNK + c];
        float2 bc = ((const float2*)Bc)[((size_t)b * NCHUNK + c) * 256 + t];
        st.x = a * st.x + bc.x;
        st.y = a * st.y + bc.y;
    }
}

__global__ __launch_bounds__(256) void scan_c(
    const float* __restrict__ h, const float* __restrict__ p,
    const float* __restrict__ res, const float* __restrict__ carry,
    float* __restrict__ out)
{
    const int t = threadIdx.x;
    const int c = blockIdx.x, b = blockIdx.y;
    const int l0 = c * CHUNK;
    const float* pb = p + (size_t)b * L_ + l0;
    const size_t base = ((size_t)b * L_ + l0) * 256 + t;   // float2 units
    const float2* hb = (const float2*)h + base;
    const float2* rb = (const float2*)res + base;
    float2* ob = (float2*)out + base;

    float2 st = ((const float2*)carry)[((size_t)b * NCHUNK + c) * 256 + t];
#pragma unroll 4
    for (int i = 0; i < CHUNK; ++i) {
        float pr = pb[i];
        float2 hv = hb[(size_t)i * 256];
        float2 rv = rb[(size_t)i * 256];
        bool sel = pr > 0.5f;
        float a = sel ? 1.f - pr : 1.f;
        float g = sel ? pr : 0.f;
        st.x = a * st.x + g * hv.x;
        st.y = a * st.y + g * hv.y;
        float2 ov; ov.x = rv.x + st.x; ov.y = rv.y + st.y;
        ob[(size_t)i * 256] = ov;
    }
}

// ---------------------------------------------------------------------------
extern "C" void kernel_launch(void* const* d_in, const int* in_sizes, int n_in,
                              void* d_out, int out_size, void* d_ws, size_t ws_size,
                              hipStream_t stream)
{
    const float* h   = (const float*)d_in[0];
    const float* res = (const float*)d_in[1];
    const float* wq  = (const float*)d_in[2];
    const float* wk  = (const float*)d_in[3];
    const float* det = (const float*)d_in[4];
    float* out = (float*)d_out;

    // ws layout (floats)
    float* ws = (float*)d_ws;
    float* part  = ws;                                     // NCT*B*L*3 = 393216
    float* p     = part + (size_t)NCT * B_ * L_ * 3;       // 32768
    float* Ac    = p + (size_t)B_ * L_;                    // 512
    float* Bc    = Ac + (size_t)B_ * NCHUNK;               // 262144
    float* carry = Bc + (size_t)B_ * NCHUNK * D_;          // 262144
    int*  fix_cnt  = (int*)(carry + (size_t)B_ * NCHUNK * D_);
    int*  fix_list = fix_cnt + 4;                          // MAXFIX ints
    u16* wqh = (u16*)(fix_list + MAXFIX);                  // D*D u16
    u16* wkh = wqh + (size_t)D_ * D_;

    conv_w<<<(D_ * D_ + 255) / 256, 256, 0, stream>>>(wq, wk, wqh, wkh);
    zero_fix<<<1, 64, 0, stream>>>(fix_cnt);
    qk_mfma<<<dim3(NCT, NRT, B_), 256, 0, stream>>>(h, wqh, wkh, part);
    cos_reduce<<<(B_ * L_ + 255) / 256, 256, 0, stream>>>(part, p, fix_cnt, fix_list);
    fixup<<<128, 256, 0, stream>>>(h, wq, wk, fix_cnt, fix_list, p);
    scan_a<<<dim3(NCHUNK, B_), 256, 0, stream>>>(h, p, Bc, Ac);
    scan_b<<<B_, 256, 0, stream>>>(Ac, Bc, det, carry);
    scan_c<<<dim3(NCHUNK, B_), 256, 0, stream>>>(h, p, res, carry, out);
}